// Round 1
// baseline (2036.581 us; speedup 1.0000x reference)
//
#include <hip/hip_runtime.h>
#include <hip/hip_bf16.h>

// DeltaNet chunkwise delta rule, b=2 h=8 L=4096 dk=dv=128 chunk=32.
// Phase 2 (parallel, 2048 wgs): normalize, invert (I-A), u, w, att_local.
// Phase 3 (scan, 128 wgs = 16 bh-chains x 8 dv-column-blocks of 16):
//   the S recurrence is column-separable in dv.

#define B 2
#define H 8
#define LSEQ 4096
#define DK 128
#define DV 128
#define C 32
#define NCHUNK (LSEQ / C)      // 128
#define BH (B * H)             // 16
#define NBLK (BH * NCHUNK)     // 2048
#define LDP 132                // padded LDS row stride for 32x128 tiles
#define DVB 16                 // dv columns per scan chain
#define NCB (DV / DVB)         // 8

__global__ __launch_bounds__(256) void phase2_kernel(
    const float* __restrict__ q, const float* __restrict__ k,
    const float* __restrict__ v, const float* __restrict__ beta,
    float* __restrict__ u_out, float* __restrict__ w_out,
    float* __restrict__ attl_out)
{
    __shared__ float sq[C * LDP];   // normalized q
    __shared__ float sk[C * LDP];   // normalized k
    __shared__ float svb[C * LDP];  // v * beta
    __shared__ float skb[C * LDP];  // k_norm * beta
    __shared__ float satt[C * 33];
    __shared__ float sbeta[C];
    __shared__ float sscq[C], ssck[C];

    const int t = threadIdx.x;
    const int blk = blockIdx.x;          // 0..2047
    const int bh = blk / NCHUNK;
    const int nc = blk % NCHUNK;
    const long base = ((long)bh * LSEQ + (long)nc * C) * DK;

    // load 32x128 q,k,v (16 floats/thread)
    {
        int r = t >> 3;
        int c0 = (t & 7) * 16;
        const float* qp = q + base + r * DK + c0;
        const float* kp = k + base + r * DK + c0;
        const float* vp = v + base + r * DK + c0;
        #pragma unroll
        for (int i = 0; i < 16; i++) {
            sq[r * LDP + c0 + i]  = qp[i];
            sk[r * LDP + c0 + i]  = kp[i];
            svb[r * LDP + c0 + i] = vp[i];
        }
        if (t < C) sbeta[t] = beta[(long)bh * LSEQ + (long)nc * C + t];
    }
    __syncthreads();
    // row l2-norm scales
    if (t < C) {
        float s1 = 0.f, s2 = 0.f;
        const float* qr = sq + t * LDP;
        const float* kr = sk + t * LDP;
        #pragma unroll 4
        for (int j = 0; j < DK; j++) { s1 += qr[j] * qr[j]; s2 += kr[j] * kr[j]; }
        sscq[t] = 1.0f / sqrtf(s1 + 1e-6f);
        ssck[t] = 1.0f / sqrtf(s2 + 1e-6f);
    }
    __syncthreads();
    // apply scales; build kb, vb
    {
        int r = t >> 3;
        int c0 = (t & 7) * 16;
        float cq = sscq[r], ck = ssck[r], bt = sbeta[r];
        #pragma unroll
        for (int i = 0; i < 16; i++) {
            sq[r * LDP + c0 + i] *= cq;
            float kn = sk[r * LDP + c0 + i] * ck;
            sk[r * LDP + c0 + i]  = kn;
            skb[r * LDP + c0 + i] = kn * bt;
            svb[r * LDP + c0 + i] *= bt;
        }
    }
    __syncthreads();
    // att_raw[r][s] = -(kb[r].kn[s]) for s<r else 0  (4 entries/thread)
    {
        int s = t & 31;
        int rg = t >> 5;   // 0..7
        #pragma unroll
        for (int ii = 0; ii < 4; ii++) {
            int r = rg + ii * 8;
            float acc = 0.f;
            if (s < r) {
                const float* a  = skb + r * LDP;
                const float* bb = sk + s * LDP;
                #pragma unroll 4
                for (int j = 0; j < DK; j++) acc += a[j] * bb[j];
                acc = -acc;
            }
            satt[r * 33 + s] = acc;
        }
    }
    __syncthreads();
    // forward substitution: in-place invert (I - A) lower part
    for (int i = 1; i < C; i++) {
        float upd = 0.f;
        if (t < i) {
            for (int j = t + 1; j < i; j++)
                upd += satt[i * 33 + j] * satt[j * 33 + t];
        }
        __syncthreads();
        if (t < i) satt[i * 33 + t] += upd;
        __syncthreads();
    }
    // + I, then bf16 round (matches reference .astype(bf16).astype(f32))
    if (t < C) satt[t * 33 + t] = 1.0f;
    __syncthreads();
    {
        int s = t & 31;
        int rg = t >> 5;
        #pragma unroll
        for (int ii = 0; ii < 4; ii++) {
            int r = rg + ii * 8;
            satt[r * 33 + s] = __bfloat162float(__float2bfloat16(satt[r * 33 + s]));
        }
    }
    __syncthreads();
    // u = att @ vb ; w = att @ kb  (thread: row r, 16-col segment)
    {
        int r = t >> 3;
        int c0 = (t & 7) * 16;
        float uacc[16], wacc[16];
        #pragma unroll
        for (int i = 0; i < 16; i++) { uacc[i] = 0.f; wacc[i] = 0.f; }
        for (int s = 0; s < C; s++) {
            float a = satt[r * 33 + s];
            const float* vp = svb + s * LDP + c0;
            const float* kp = skb + s * LDP + c0;
            #pragma unroll
            for (int i = 0; i < 16; i++) {
                uacc[i] += a * vp[i];
                wacc[i] += a * kp[i];
            }
        }
        long ob = (long)blk * (C * DV) + (long)r * DV + c0;
        #pragma unroll
        for (int i = 0; i < 16; i++) {
            u_out[ob + i] = uacc[i];
            w_out[ob + i] = wacc[i];
        }
    }
    // att_local = tril(qn @ kn^T) incl diag
    {
        int s = t & 31;
        int rg = t >> 5;
        #pragma unroll
        for (int ii = 0; ii < 4; ii++) {
            int r = rg + ii * 8;
            float acc = 0.f;
            if (s <= r) {
                const float* a  = sq + r * LDP;
                const float* bb = sk + s * LDP;
                #pragma unroll 4
                for (int j = 0; j < DK; j++) acc += a[j] * bb[j];
            }
            attl_out[(long)blk * (C * C) + r * C + s] = acc;
        }
    }
}

__global__ __launch_bounds__(256) void phase3_kernel(
    const float* __restrict__ q, const float* __restrict__ k,
    const float* __restrict__ u_in, const float* __restrict__ w_in,
    const float* __restrict__ attl_in,
    float* __restrict__ o_out, float* __restrict__ S_out)
{
    __shared__ float sq[C * LDP];
    __shared__ float sk[C * LDP];
    __shared__ float sw[C * LDP];
    __shared__ float sattl[C * C];
    __shared__ float su[C * DVB];
    __shared__ float sun[C * DVB];
    __shared__ float sS[DK * DVB];
    __shared__ float sscq[C], ssck[C];

    const int t = threadIdx.x;
    const int wg = blockIdx.x;    // 0..127
    const int bh = wg >> 3;
    const int cb = wg & 7;
    const int col0 = cb * DVB;

    for (int i = t; i < DK * DVB; i += 256) sS[i] = 0.f;

    const int cc = t & 15;
    const int rg = t >> 4;   // 0..15
    __syncthreads();

    for (int nc = 0; nc < NCHUNK; nc++) {
        const long blk = (long)bh * NCHUNK + nc;
        const long base = ((long)bh * LSEQ + (long)nc * C) * DK;
        // cooperative loads
        {
            int r = t >> 3;
            int c0 = (t & 7) * 16;
            const float* qp = q + base + r * DK + c0;
            const float* kp = k + base + r * DK + c0;
            const float* wp = w_in + blk * (C * DK) + r * DK + c0;
            #pragma unroll
            for (int i = 0; i < 16; i++) {
                sq[r * LDP + c0 + i] = qp[i];
                sk[r * LDP + c0 + i] = kp[i];
                sw[r * LDP + c0 + i] = wp[i];
            }
            #pragma unroll
            for (int i = 0; i < 4; i++)
                sattl[t * 4 + i] = attl_in[blk * (C * C) + t * 4 + i];
            int ur = t >> 3;
            int uc = (t & 7) * 2;
            su[ur * DVB + uc]     = u_in[blk * (C * DV) + (long)ur * DV + col0 + uc];
            su[ur * DVB + uc + 1] = u_in[blk * (C * DV) + (long)ur * DV + col0 + uc + 1];
        }
        __syncthreads();
        if (t < C) {
            float s1 = 0.f, s2 = 0.f;
            const float* qr = sq + t * LDP;
            const float* kr = sk + t * LDP;
            #pragma unroll 4
            for (int j = 0; j < DK; j++) { s1 += qr[j]*qr[j]; s2 += kr[j]*kr[j]; }
            sscq[t] = 1.0f / sqrtf(s1 + 1e-6f);
            ssck[t] = 1.0f / sqrtf(s2 + 1e-6f);
        }
        __syncthreads();
        {
            int r = t >> 3;
            int c0 = (t & 7) * 16;
            float cq = sscq[r], ck = ssck[r];
            #pragma unroll
            for (int i = 0; i < 16; i++) {
                sq[r * LDP + c0 + i] *= cq;
                sk[r * LDP + c0 + i] *= ck;
            }
        }
        __syncthreads();
        // u_new = u - w @ S   (rows rg, rg+16; col cc)
        {
            int r0 = rg, r1 = rg + 16;
            float a0 = 0.f, a1 = 0.f;
            #pragma unroll 4
            for (int j = 0; j < DK; j++) {
                float sv = sS[j * DVB + cc];
                a0 += sw[r0 * LDP + j] * sv;
                a1 += sw[r1 * LDP + j] * sv;
            }
            sun[r0 * DVB + cc] = su[r0 * DVB + cc] - a0;
            sun[r1 * DVB + cc] = su[r1 * DVB + cc] - a1;
        }
        __syncthreads();
        // o = q @ S + attl @ u_new  -> global
        {
            int r0 = rg, r1 = rg + 16;
            float a0 = 0.f, a1 = 0.f;
            #pragma unroll 4
            for (int j = 0; j < DK; j++) {
                float sv = sS[j * DVB + cc];
                a0 += sq[r0 * LDP + j] * sv;
                a1 += sq[r1 * LDP + j] * sv;
            }
            #pragma unroll 4
            for (int s = 0; s < C; s++) {
                float uv = sun[s * DVB + cc];
                a0 += sattl[r0 * C + s] * uv;
                a1 += sattl[r1 * C + s] * uv;
            }
            long ob = ((long)bh * LSEQ + (long)nc * C) * DV + col0 + cc;
            o_out[ob + (long)r0 * DV] = a0;
            o_out[ob + (long)r1 * DV] = a1;
        }
        __syncthreads();   // all reads of old S done
        // S += k^T @ u_new
        {
            #pragma unroll
            for (int ii = 0; ii < 8; ii++) {
                int j = rg + ii * 16;
                float acc = 0.f;
                #pragma unroll 4
                for (int r = 0; r < C; r++)
                    acc += sk[r * LDP + j] * sun[r * DVB + cc];
                sS[j * DVB + cc] += acc;
            }
        }
        __syncthreads();
    }
    // final S block
    {
        #pragma unroll
        for (int ii = 0; ii < 8; ii++) {
            int j = rg + ii * 16;
            S_out[(long)bh * (DK * DV) + (long)j * DV + col0 + cc] = sS[j * DVB + cc];
        }
    }
}

extern "C" void kernel_launch(void* const* d_in, const int* in_sizes, int n_in,
                              void* d_out, int out_size, void* d_ws, size_t ws_size,
                              hipStream_t stream) {
    const float* q    = (const float*)d_in[0];
    const float* k    = (const float*)d_in[1];
    const float* v    = (const float*)d_in[2];
    const float* beta = (const float*)d_in[3];

    float* o = (float*)d_out;                      // [b,h,L,dv]
    float* S = o + (long)BH * LSEQ * DV;           // [b,h,dk,dv]

    // workspace: u (32MB) + w (32MB) + att_local (8MB) = 75.5MB
    float* u_ws    = (float*)d_ws;
    float* w_ws    = u_ws + (long)NBLK * C * DV;
    float* attl_ws = w_ws + (long)NBLK * C * DK;

    phase2_kernel<<<NBLK, 256, 0, stream>>>(q, k, v, beta, u_ws, w_ws, attl_ws);
    phase3_kernel<<<BH * NCB, 256, 0, stream>>>(q, k, u_ws, w_ws, attl_ws, o, S);
}

// Round 2
// 580.811 us; speedup vs baseline: 3.5064x; 3.5064x over previous
//
#include <hip/hip_runtime.h>
#include <hip/hip_bf16.h>
#include <hip/hip_fp16.h>

// DeltaNet chunkwise delta rule, b=2 h=8 L=4096 dk=dv=128 chunk=32.
// Phase2 (2048 wgs, fp32): norm, (I-A)^-1, bf16-round, u/w/attl; emits fp16
//   MFMA fragment files (A-frag lane order) + u in C-frag order.
// Phase3 (16 wgs x 512 thr): per-bh scan, S in MFMA accumulators, fp16 MFMA.

#define B 2
#define H 8
#define LSEQ 4096
#define DK 128
#define DV 128
#define C 32
#define NCHUNK (LSEQ / C)      // 128
#define BH (B * H)             // 16
#define NBLK (BH * NCHUNK)     // 2048
#define LDP 132                // padded fp32 LDS row stride

typedef _Float16 f16x8 __attribute__((ext_vector_type(8)));
typedef float f32x4 __attribute__((ext_vector_type(4)));

union U4H8 { uint4 u; f16x8 h; };

__device__ inline unsigned short f2h(float f) {
    _Float16 h = (_Float16)f;
    unsigned short u;
    __builtin_memcpy(&u, &h, 2);
    return u;
}
__device__ inline float h2f(unsigned int v) {
    unsigned short s = (unsigned short)v;
    _Float16 h;
    __builtin_memcpy(&h, &s, 2);
    return (float)h;
}
__device__ inline unsigned int pack2(float a, float b) {
    return (unsigned int)f2h(a) | ((unsigned int)f2h(b) << 16);
}
__device__ inline float dot4(float4 a, float4 b) {
    return a.x * b.x + a.y * b.y + a.z * b.z + a.w * b.w;
}

// ---------------- Phase 2 ----------------
__global__ __launch_bounds__(256) void phase2_kernel(
    const float* __restrict__ q, const float* __restrict__ k,
    const float* __restrict__ v, const float* __restrict__ beta,
    uint4* __restrict__ wnegf, uint4* __restrict__ qnf,
    uint4* __restrict__ ktf, uint4* __restrict__ atf,
    uint2* __restrict__ uf)
{
    __shared__ float sQ[C * LDP];   // qn; reused for w after qn16 written
    __shared__ float sK[C * LDP];   // kn
    __shared__ float sV[C * LDP];   // raw v
    __shared__ float sU[C * LDP];   // u
    __shared__ float satt[C * 33];
    __shared__ float sattl[C * 33];
    __shared__ float sbeta[C];
    __shared__ float sred[C * 16];

    const int t = threadIdx.x;
    const int blk = blockIdx.x;
    const int r8 = t >> 3;          // row 0..31
    const int sg = t & 7;
    const int c16 = sg * 16;
    const long gbase = ((long)blk * C + r8) * DK + c16;

    // load q,k,v (16 floats each) into regs; partial norms; v -> LDS
    float4 qv[4], kv[4], vv[4];
    float sqs = 0.f, sks = 0.f;
    #pragma unroll
    for (int i = 0; i < 4; i++) {
        qv[i] = *(const float4*)(q + gbase + i * 4);
        kv[i] = *(const float4*)(k + gbase + i * 4);
        vv[i] = *(const float4*)(v + gbase + i * 4);
        sqs += dot4(qv[i], qv[i]);
        sks += dot4(kv[i], kv[i]);
        *(float4*)&sV[r8 * LDP + c16 + i * 4] = vv[i];
    }
    sred[r8 * 8 + sg] = sqs;
    sred[256 + r8 * 8 + sg] = sks;
    if (t < C) sbeta[t] = beta[(long)blk * C + t];
    __syncthreads();
    float s1 = 0.f, s2 = 0.f;
    #pragma unroll
    for (int j = 0; j < 8; j++) { s1 += sred[r8 * 8 + j]; s2 += sred[256 + r8 * 8 + j]; }
    const float qsc = rsqrtf(s1 + 1e-6f);
    const float ksc = rsqrtf(s2 + 1e-6f);
    #pragma unroll
    for (int i = 0; i < 4; i++) {
        float4 a = qv[i];
        a.x *= qsc; a.y *= qsc; a.z *= qsc; a.w *= qsc;
        *(float4*)&sQ[r8 * LDP + c16 + i * 4] = a;
        float4 bb = kv[i];
        bb.x *= ksc; bb.y *= ksc; bb.z *= ksc; bb.w *= ksc;
        *(float4*)&sK[r8 * LDP + c16 + i * 4] = bb;
    }
    __syncthreads();

    // attl = tril(qn@kn^T) incl diag; att_raw = -beta[r]*(kn_r . kn_s) strict lower
    {
        const int rp = t >> 4, sp = t & 15;
        const int rr0 = rp, rr1 = rp + 16;
        const int ss0 = sp, ss1 = sp + 16;
        float aqq00 = 0.f, aqq01 = 0.f, aqq10 = 0.f, aqq11 = 0.f;
        float akk00 = 0.f, akk01 = 0.f, akk10 = 0.f, akk11 = 0.f;
        for (int j = 0; j < DK; j += 4) {
            float4 q0 = *(float4*)&sQ[rr0 * LDP + j];
            float4 q1 = *(float4*)&sQ[rr1 * LDP + j];
            float4 k0 = *(float4*)&sK[rr0 * LDP + j];
            float4 k1 = *(float4*)&sK[rr1 * LDP + j];
            float4 cv0 = *(float4*)&sK[ss0 * LDP + j];
            float4 cv1 = *(float4*)&sK[ss1 * LDP + j];
            aqq00 += dot4(q0, cv0); aqq01 += dot4(q0, cv1);
            aqq10 += dot4(q1, cv0); aqq11 += dot4(q1, cv1);
            akk00 += dot4(k0, cv0); akk01 += dot4(k0, cv1);
            akk10 += dot4(k1, cv0); akk11 += dot4(k1, cv1);
        }
        float b0 = sbeta[rr0], b1 = sbeta[rr1];
        sattl[rr0 * 33 + ss0] = (ss0 <= rr0) ? aqq00 : 0.f;
        sattl[rr0 * 33 + ss1] = (ss1 <= rr0) ? aqq01 : 0.f;
        sattl[rr1 * 33 + ss0] = (ss0 <= rr1) ? aqq10 : 0.f;
        sattl[rr1 * 33 + ss1] = (ss1 <= rr1) ? aqq11 : 0.f;
        satt[rr0 * 33 + ss0] = (ss0 < rr0) ? (-b0 * akk00) : 0.f;
        satt[rr0 * 33 + ss1] = (ss1 < rr0) ? (-b0 * akk01) : 0.f;
        satt[rr1 * 33 + ss0] = (ss0 < rr1) ? (-b1 * akk10) : 0.f;
        satt[rr1 * 33 + ss1] = (ss1 < rr1) ? (-b1 * akk11) : 0.f;
    }
    __syncthreads();

    // qn16 A-frag file (reads sQ)
    #pragma unroll
    for (int i = 0; i < 2; i++) {
        int slot = t + i * 256;
        int lane = slot & 63, kt = (slot >> 6) & 3, mt2 = (slot >> 8) & 1;
        int m = mt2 * 16 + (lane & 15);
        int kk = kt * 32 + ((lane >> 4) & 3) * 8;
        float4 x0 = *(float4*)&sQ[m * LDP + kk];
        float4 x1 = *(float4*)&sQ[m * LDP + kk + 4];
        uint4 o4;
        o4.x = pack2(x0.x, x0.y); o4.y = pack2(x0.z, x0.w);
        o4.z = pack2(x1.x, x1.y); o4.w = pack2(x1.z, x1.w);
        qnf[((long)blk * 8 + mt2 * 4 + kt) * 64 + lane] = o4;
    }
    // kT16 A-frag file (reads sK): A[m=dk][k=s]
    #pragma unroll
    for (int i = 0; i < 2; i++) {
        int slot = t + i * 256;
        int lane = slot & 63, mt = (slot >> 6) & 7;
        int dki = mt * 16 + (lane & 15);
        int s0 = ((lane >> 4) & 3) * 8;
        float x[8];
        #pragma unroll
        for (int j = 0; j < 8; j++) x[j] = sK[(s0 + j) * LDP + dki];
        uint4 o4;
        o4.x = pack2(x[0], x[1]); o4.y = pack2(x[2], x[3]);
        o4.z = pack2(x[4], x[5]); o4.w = pack2(x[6], x[7]);
        ktf[((long)blk * 8 + mt) * 64 + lane] = o4;
    }
    // attl16 A-frag file
    if (t < 128) {
        int lane = t & 63, mt2 = t >> 6;
        int m = mt2 * 16 + (lane & 15);
        int s0 = ((lane >> 4) & 3) * 8;
        float x[8];
        #pragma unroll
        for (int j = 0; j < 8; j++) x[j] = sattl[m * 33 + s0 + j];
        uint4 o4;
        o4.x = pack2(x[0], x[1]); o4.y = pack2(x[2], x[3]);
        o4.z = pack2(x[4], x[5]); o4.w = pack2(x[6], x[7]);
        atf[((long)blk * 2 + mt2) * 64 + lane] = o4;
    }

    // forward substitution: invert (I - A)
    for (int i = 1; i < C; i++) {
        float upd = 0.f;
        if (t < i) {
            for (int j = t + 1; j < i; j++)
                upd += satt[i * 33 + j] * satt[j * 33 + t];
        }
        __syncthreads();
        if (t < i) satt[i * 33 + t] += upd;
        __syncthreads();
    }
    if (t < C) satt[t * 33 + t] = 1.0f;
    __syncthreads();
    #pragma unroll
    for (int i = 0; i < 4; i++) {
        int idx = t * 4 + i;
        int r = idx >> 5, s2 = idx & 31;
        satt[r * 33 + s2] = __bfloat162float(__float2bfloat16(satt[r * 33 + s2]));
    }
    __syncthreads();

    // u = att @ (v*beta) -> sU ; w = att @ (kn*beta) -> sQ (reuse)
    {
        const int rp = t >> 4;
        const int cg = t & 15;
        const int cc0 = cg * 8;
        float ua0[8], ua1[8], wa0[8], wa1[8];
        #pragma unroll
        for (int j = 0; j < 8; j++) { ua0[j] = 0.f; ua1[j] = 0.f; wa0[j] = 0.f; wa1[j] = 0.f; }
        for (int s = 0; s < C; s++) {
            float bs = sbeta[s];
            float a0 = satt[rp * 33 + s] * bs;
            float a1 = satt[(rp + 16) * 33 + s] * bs;
            float vv8[8], kk8[8];
            *(float4*)&vv8[0] = *(float4*)&sV[s * LDP + cc0];
            *(float4*)&vv8[4] = *(float4*)&sV[s * LDP + cc0 + 4];
            *(float4*)&kk8[0] = *(float4*)&sK[s * LDP + cc0];
            *(float4*)&kk8[4] = *(float4*)&sK[s * LDP + cc0 + 4];
            #pragma unroll
            for (int j = 0; j < 8; j++) {
                ua0[j] += a0 * vv8[j]; ua1[j] += a1 * vv8[j];
                wa0[j] += a0 * kk8[j]; wa1[j] += a1 * kk8[j];
            }
        }
        #pragma unroll
        for (int j = 0; j < 8; j++) {
            sU[rp * LDP + cc0 + j] = ua0[j];
            sU[(rp + 16) * LDP + cc0 + j] = ua1[j];
            sQ[rp * LDP + cc0 + j] = wa0[j];
            sQ[(rp + 16) * LDP + cc0 + j] = wa1[j];
        }
    }
    __syncthreads();

    // wneg16 A-frag file (reads sQ = w, negated)
    #pragma unroll
    for (int i = 0; i < 2; i++) {
        int slot = t + i * 256;
        int lane = slot & 63, kt = (slot >> 6) & 3, mt2 = (slot >> 8) & 1;
        int m = mt2 * 16 + (lane & 15);
        int kk = kt * 32 + ((lane >> 4) & 3) * 8;
        float4 x0 = *(float4*)&sQ[m * LDP + kk];
        float4 x1 = *(float4*)&sQ[m * LDP + kk + 4];
        uint4 o4;
        o4.x = pack2(-x0.x, -x0.y); o4.y = pack2(-x0.z, -x0.w);
        o4.z = pack2(-x1.x, -x1.y); o4.w = pack2(-x1.z, -x1.w);
        wnegf[((long)blk * 8 + mt2 * 4 + kt) * 64 + lane] = o4;
    }
    // u C-frag file
    #pragma unroll
    for (int i = 0; i < 4; i++) {
        int slot = t + i * 256;
        int lane = slot & 63, ntt = (slot >> 6) & 7, mt2 = (slot >> 9) & 1;
        int quad = (lane >> 4) & 3;
        int m0 = mt2 * 16 + quad * 4;
        int col = ntt * 16 + (lane & 15);
        uint2 o2;
        o2.x = pack2(sU[(m0 + 0) * LDP + col], sU[(m0 + 1) * LDP + col]);
        o2.y = pack2(sU[(m0 + 2) * LDP + col], sU[(m0 + 3) * LDP + col]);
        uf[(((long)blk * 2 + mt2) * 8 + ntt) * 64 + lane] = o2;
    }
}

// ---------------- Phase 3 ----------------
__global__ __launch_bounds__(512, 2) void phase3_kernel(
    const uint4* __restrict__ wnegf, const uint4* __restrict__ qnf,
    const uint4* __restrict__ ktf, const uint4* __restrict__ atf,
    const uint2* __restrict__ uf,
    float* __restrict__ o_out, float* __restrict__ S_out)
{
    __shared__ alignas(16) _Float16 S16[128 * 136];  // [dv][dk], 16B-granule XOR swizzle
    __shared__ alignas(16) _Float16 U16[128 * 40];   // [dv][s]

    const int t = threadIdx.x;
    const int w = t >> 6;          // wave 0..7, owns dv tile nt=w
    const int l = t & 63;
    const int lm = l & 15;
    const int quad = l >> 4;
    const int bh = blockIdx.x;
    const int dv = w * 16 + lm;
    const int dvl = dv & 7;

    f32x4 accS[8];
    #pragma unroll
    for (int mt = 0; mt < 8; mt++) accS[mt] = (f32x4){0.f, 0.f, 0.f, 0.f};

    for (int nc = 0; nc < NCHUNK; nc++) {
        const long blk = (long)bh * NCHUNK + nc;
        // global frag prefetch (coalesced dwordx4, consumed after barriers)
        uint4 aW[2][4], aQ[2][4], aK[8], aAt[2];
        uint2 aU[2];
        #pragma unroll
        for (int mt2 = 0; mt2 < 2; mt2++) {
            #pragma unroll
            for (int kt = 0; kt < 4; kt++) {
                aW[mt2][kt] = wnegf[(blk * 8 + mt2 * 4 + kt) * 64 + l];
                aQ[mt2][kt] = qnf[(blk * 8 + mt2 * 4 + kt) * 64 + l];
            }
            aAt[mt2] = atf[(blk * 2 + mt2) * 64 + l];
            aU[mt2] = uf[((blk * 2 + mt2) * 8 + w) * 64 + l];
        }
        #pragma unroll
        for (int mt = 0; mt < 8; mt++) aK[mt] = ktf[(blk * 8 + mt) * 64 + l];

        // Stage A: accS (fp32 C-layout) -> S16 fp16 [dv][dk] swizzled
        #pragma unroll
        for (int mt = 0; mt < 8; mt++) {
            int dk0 = mt * 16 + quad * 4;
            int phys = (dk0 >> 3) ^ dvl;
            int sub = dk0 & 7;
            uint2 p;
            p.x = pack2(accS[mt][0], accS[mt][1]);
            p.y = pack2(accS[mt][2], accS[mt][3]);
            *(uint2*)&S16[dv * 136 + phys * 8 + sub] = p;
        }
        __syncthreads();   // B1: S16 visible; prev-iter U16 readers done

        // Stage B: u_new = u + (-w)@S ; o_part = q@S
        f32x4 accU[2], accO[2];
        #pragma unroll
        for (int mt2 = 0; mt2 < 2; mt2++) {
            accU[mt2][0] = h2f(aU[mt2].x & 0xffffu);
            accU[mt2][1] = h2f(aU[mt2].x >> 16);
            accU[mt2][2] = h2f(aU[mt2].y & 0xffffu);
            accU[mt2][3] = h2f(aU[mt2].y >> 16);
            accO[mt2] = (f32x4){0.f, 0.f, 0.f, 0.f};
        }
        #pragma unroll
        for (int kt = 0; kt < 4; kt++) {
            int phys = (kt * 4 + quad) ^ dvl;
            U4H8 bs;
            bs.u = *(const uint4*)&S16[dv * 136 + phys * 8];
            #pragma unroll
            for (int mt2 = 0; mt2 < 2; mt2++) {
                U4H8 aw, aq;
                aw.u = aW[mt2][kt];
                aq.u = aQ[mt2][kt];
                accU[mt2] = __builtin_amdgcn_mfma_f32_16x16x32_f16(aw.h, bs.h, accU[mt2], 0, 0, 0);
                accO[mt2] = __builtin_amdgcn_mfma_f32_16x16x32_f16(aq.h, bs.h, accO[mt2], 0, 0, 0);
            }
        }
        // Stage C: u_new -> U16 fp16 [dv][s]
        #pragma unroll
        for (int mt2 = 0; mt2 < 2; mt2++) {
            int s0 = mt2 * 16 + quad * 4;
            uint2 p;
            p.x = pack2(accU[mt2][0], accU[mt2][1]);
            p.y = pack2(accU[mt2][2], accU[mt2][3]);
            *(uint2*)&U16[dv * 40 + s0] = p;
        }
        __syncthreads();   // B2: U16 visible; all S16 reads done

        // Stage D: o += attl @ u_new; store o
        U4H8 bu;
        bu.u = *(const uint4*)&U16[dv * 40 + quad * 8];
        const long ob = ((long)bh * LSEQ + (long)nc * C) * DV;
        #pragma unroll
        for (int mt2 = 0; mt2 < 2; mt2++) {
            U4H8 aa;
            aa.u = aAt[mt2];
            accO[mt2] = __builtin_amdgcn_mfma_f32_16x16x32_f16(aa.h, bu.h, accO[mt2], 0, 0, 0);
            #pragma unroll
            for (int r = 0; r < 4; r++)
                o_out[ob + (long)(mt2 * 16 + quad * 4 + r) * DV + dv] = accO[mt2][r];
        }
        // Stage E: S += kT @ u_new
        #pragma unroll
        for (int mt = 0; mt < 8; mt++) {
            U4H8 ak;
            ak.u = aK[mt];
            accS[mt] = __builtin_amdgcn_mfma_f32_16x16x32_f16(ak.h, bu.h, accS[mt], 0, 0, 0);
        }
    }
    // final S
    #pragma unroll
    for (int mt = 0; mt < 8; mt++) {
        #pragma unroll
        for (int r = 0; r < 4; r++)
            S_out[(long)bh * (DK * DV) + (long)(mt * 16 + quad * 4 + r) * DV + dv] = accS[mt][r];
    }
}

extern "C" void kernel_launch(void* const* d_in, const int* in_sizes, int n_in,
                              void* d_out, int out_size, void* d_ws, size_t ws_size,
                              hipStream_t stream) {
    const float* q    = (const float*)d_in[0];
    const float* k    = (const float*)d_in[1];
    const float* v    = (const float*)d_in[2];
    const float* beta = (const float*)d_in[3];

    float* o = (float*)d_out;                      // [b,h,L,dv]
    float* S = o + (long)BH * LSEQ * DV;           // [b,h,dk,dv]

    // workspace: wneg16 16.8MB + qn16 16.8MB + kT16 16.8MB + attl16 4.2MB + u16 16.8MB = 71.3MB
    const size_t nwq = (size_t)NBLK * 8 * 64;      // uint4 per A-frag file
    uint4* wnegf = (uint4*)d_ws;
    uint4* qnf = wnegf + nwq;
    uint4* ktf = qnf + nwq;
    uint4* atf = ktf + nwq;                        // uses NBLK*2*64 uint4
    uint2* uf  = (uint2*)(atf + (size_t)NBLK * 2 * 64);

    phase2_kernel<<<NBLK, 256, 0, stream>>>(q, k, v, beta, wnegf, qnf, ktf, atf, uf);
    phase3_kernel<<<BH, 512, 0, stream>>>(wnegf, qnf, ktf, atf, uf, o, S);
}

// Round 3
// 250.117 us; speedup vs baseline: 8.1425x; 2.3222x over previous
//
#include <hip/hip_runtime.h>
#include <hip/hip_bf16.h>

// DeltaNet chunkwise delta rule, b=2 h=8 L=4096 dk=dv=128 chunk=32.
// Phase2 (2048 wgs x 256 thr): all-MFMA chunk-local pass. Computes qn,kn,
//   att=-beta*(kn@knT), attl=tril(qn@knT), T=(I-A)^-1 via nilpotent doubling
//   (I+A)(I+A^2)(I+A^4)(I+A^8)(I+A^16), bf16-round, u/w via Tb=T*diag(beta).
//   Emits fp16 MFMA fragment files (A-frag order) + u in C-frag order.
// Phase3 (128 wgs x 64 thr = 1 wave): per-(bh,dv-stripe) scan. S in MFMA
//   accumulators; no barriers (wave-synchronous LDS); 2-deep register
//   prefetch of next chunk's frags. blockIdx = stripe*16+bh so the 8 wgs of
//   one bh share an XCD L2 (bh mod 8 = XCD heuristic).

#define B 2
#define H 8
#define LSEQ 4096
#define DK 128
#define DV 128
#define C 32
#define NCHUNK (LSEQ / C)      // 128
#define BH (B * H)             // 16
#define NBLK (BH * NCHUNK)     // 2048

typedef _Float16 f16x8 __attribute__((ext_vector_type(8)));
typedef float f32x4 __attribute__((ext_vector_type(4)));

union U4H8 { uint4 u; f16x8 h; };

__device__ inline unsigned short f2h(float f) {
    _Float16 h = (_Float16)f;
    unsigned short u;
    __builtin_memcpy(&u, &h, 2);
    return u;
}
__device__ inline float h2f(unsigned int v) {
    unsigned short s = (unsigned short)v;
    _Float16 h;
    __builtin_memcpy(&h, &s, 2);
    return (float)h;
}
__device__ inline unsigned int pack2(float a, float b) {
    return (unsigned int)f2h(a) | ((unsigned int)f2h(b) << 16);
}
__device__ inline float dot4(float4 a, float4 b) {
    return a.x * b.x + a.y * b.y + a.z * b.z + a.w * b.w;
}

// ---------------- Phase 2 ----------------
__global__ __launch_bounds__(256, 3) void phase2_kernel(
    const float* __restrict__ q, const float* __restrict__ k,
    const float* __restrict__ v, const float* __restrict__ beta,
    uint4* __restrict__ wnegf, uint4* __restrict__ qnf,
    uint4* __restrict__ ktf, uint4* __restrict__ atf,
    uint2* __restrict__ uf)
{
    __shared__ alignas(16) _Float16 Qh[32 * 136];  // qn rows; reused for -w
    __shared__ alignas(16) _Float16 Kh[32 * 136];  // kn rows
    __shared__ alignas(16) _Float16 VT[128 * 40];  // v^T  [dv][s]
    __shared__ alignas(16) _Float16 KT[128 * 40];  // kn^T [dk][s]
    __shared__ alignas(16) _Float16 Ah[32 * 40];   // A^p; later Tb
    __shared__ alignas(16) _Float16 Th[32 * 40];   // T
    __shared__ alignas(16) _Float16 ALh[32 * 40];  // attl
    __shared__ float sredQ[256], sredK[256];
    __shared__ float sbeta[32];

    const int t = threadIdx.x;
    const int blk = blockIdx.x;
    const int wv = t >> 6, l = t & 63, lm = l & 15, quad = l >> 4;
    const int r8 = t >> 3, sg = t & 7, c16 = sg * 16;
    const long gbase = ((long)blk * C + r8) * DK + c16;

    // load q,k,v (16 floats each); partial norms
    float4 qv[4], kv[4], vv[4];
    float sqs = 0.f, sks = 0.f;
    #pragma unroll
    for (int i = 0; i < 4; i++) {
        qv[i] = *(const float4*)(q + gbase + i * 4);
        kv[i] = *(const float4*)(k + gbase + i * 4);
        vv[i] = *(const float4*)(v + gbase + i * 4);
        sqs += dot4(qv[i], qv[i]);
        sks += dot4(kv[i], kv[i]);
    }
    sredQ[r8 * 8 + sg] = sqs;
    sredK[r8 * 8 + sg] = sks;
    if (t < 32) sbeta[t] = beta[(long)blk * C + t];
    __syncthreads();
    float s1 = 0.f, s2 = 0.f;
    #pragma unroll
    for (int j = 0; j < 8; j++) { s1 += sredQ[r8 * 8 + j]; s2 += sredK[r8 * 8 + j]; }
    const float qsc = rsqrtf(s1 + 1e-6f);
    const float ksc = rsqrtf(s2 + 1e-6f);

    // Qh,Kh rows (fp16), VT,KT columns
    {
        uint4 h0, h1;
        h0.x = pack2(qv[0].x * qsc, qv[0].y * qsc); h0.y = pack2(qv[0].z * qsc, qv[0].w * qsc);
        h0.z = pack2(qv[1].x * qsc, qv[1].y * qsc); h0.w = pack2(qv[1].z * qsc, qv[1].w * qsc);
        h1.x = pack2(qv[2].x * qsc, qv[2].y * qsc); h1.y = pack2(qv[2].z * qsc, qv[2].w * qsc);
        h1.z = pack2(qv[3].x * qsc, qv[3].y * qsc); h1.w = pack2(qv[3].z * qsc, qv[3].w * qsc);
        *(uint4*)&Qh[r8 * 136 + c16] = h0;
        *(uint4*)&Qh[r8 * 136 + c16 + 8] = h1;
        uint4 g0, g1;
        g0.x = pack2(kv[0].x * ksc, kv[0].y * ksc); g0.y = pack2(kv[0].z * ksc, kv[0].w * ksc);
        g0.z = pack2(kv[1].x * ksc, kv[1].y * ksc); g0.w = pack2(kv[1].z * ksc, kv[1].w * ksc);
        g1.x = pack2(kv[2].x * ksc, kv[2].y * ksc); g1.y = pack2(kv[2].z * ksc, kv[2].w * ksc);
        g1.z = pack2(kv[3].x * ksc, kv[3].y * ksc); g1.w = pack2(kv[3].z * ksc, kv[3].w * ksc);
        *(uint4*)&Kh[r8 * 136 + c16] = g0;
        *(uint4*)&Kh[r8 * 136 + c16 + 8] = g1;
        const float* vf = (const float*)vv;
        const float* kf = (const float*)kv;
        #pragma unroll
        for (int i = 0; i < 16; i++) {
            VT[(c16 + i) * 40 + r8] = (_Float16)vf[i];
            KT[(c16 + i) * 40 + r8] = (_Float16)(kf[i] * ksc);
        }
    }
    __syncthreads();

    const int mi = wv >> 1, ni = wv & 1;
    const int colx = ni * 16 + lm;

    // att / attl via MFMA (each wave one 16x16 tile of each)
    {
        f32x4 cAtt = {0.f, 0.f, 0.f, 0.f}, cAl = {0.f, 0.f, 0.f, 0.f};
        #pragma unroll
        for (int kt = 0; kt < 4; kt++) {
            U4H8 ka, qa, kb;
            ka.u = *(const uint4*)&Kh[(mi * 16 + lm) * 136 + kt * 32 + quad * 8];
            qa.u = *(const uint4*)&Qh[(mi * 16 + lm) * 136 + kt * 32 + quad * 8];
            kb.u = *(const uint4*)&Kh[(ni * 16 + lm) * 136 + kt * 32 + quad * 8];
            cAtt = __builtin_amdgcn_mfma_f32_16x16x32_f16(ka.h, kb.h, cAtt, 0, 0, 0);
            cAl  = __builtin_amdgcn_mfma_f32_16x16x32_f16(qa.h, kb.h, cAl, 0, 0, 0);
        }
        float4 brow = *(const float4*)&sbeta[mi * 16 + quad * 4];
        float br[4] = {brow.x, brow.y, brow.z, brow.w};
        #pragma unroll
        for (int r = 0; r < 4; r++) {
            int row = mi * 16 + quad * 4 + r;
            float av = (colx < row) ? (-br[r] * cAtt[r]) : 0.f;
            Ah[row * 40 + colx] = (_Float16)av;
            Th[row * 40 + colx] = (_Float16)((colx == row) ? 1.0f : av);
            ALh[row * 40 + colx] = (_Float16)((colx <= row) ? cAl[r] : 0.f);
        }
    }
    __syncthreads();

    // qnf / ktf / atf packs (raw fp16 b128 copies in frag order)
    #pragma unroll
    for (int i = 0; i < 2; i++) {
        int slot = t + i * 256;
        int f = slot >> 6, ln = slot & 63, flm = ln & 15, fq = ln >> 4;
        int mt2 = f >> 2, kt = f & 3;
        qnf[((long)blk * 8 + f) * 64 + ln] =
            *(const uint4*)&Qh[(mt2 * 16 + flm) * 136 + kt * 32 + fq * 8];
        ktf[((long)blk * 8 + f) * 64 + ln] =
            *(const uint4*)&KT[(f * 16 + flm) * 40 + fq * 8];
    }
    if (t < 128) {
        int f = t >> 6, ln = t & 63, flm = ln & 15, fq = ln >> 4;
        atf[((long)blk * 2 + f) * 64 + ln] =
            *(const uint4*)&ALh[(f * 16 + flm) * 40 + fq * 8];
    }

    // nilpotent doubling: T <- T + A^(2^(p+1)) T, A <- A^2, 4 steps
    #pragma unroll 1
    for (int p = 0; p < 4; p++) {
        U4H8 aA, bA;
        aA.u = *(const uint4*)&Ah[(mi * 16 + lm) * 40 + quad * 8];
        #pragma unroll
        for (int j = 0; j < 8; j++) bA.h[j] = Ah[(quad * 8 + j) * 40 + colx];
        f32x4 cA = {0.f, 0.f, 0.f, 0.f};
        cA = __builtin_amdgcn_mfma_f32_16x16x32_f16(aA.h, bA.h, cA, 0, 0, 0);
        __syncthreads();
        #pragma unroll
        for (int r = 0; r < 4; r++)
            Ah[(mi * 16 + quad * 4 + r) * 40 + colx] = (_Float16)cA[r];
        __syncthreads();
        U4H8 aA2, bT;
        aA2.u = *(const uint4*)&Ah[(mi * 16 + lm) * 40 + quad * 8];
        #pragma unroll
        for (int j = 0; j < 8; j++) bT.h[j] = Th[(quad * 8 + j) * 40 + colx];
        f32x4 cT;
        #pragma unroll
        for (int r = 0; r < 4; r++)
            cT[r] = (float)Th[(mi * 16 + quad * 4 + r) * 40 + colx];
        cT = __builtin_amdgcn_mfma_f32_16x16x32_f16(aA2.h, bT.h, cT, 0, 0, 0);
        __syncthreads();
        #pragma unroll
        for (int r = 0; r < 4; r++)
            Th[(mi * 16 + quad * 4 + r) * 40 + colx] = (_Float16)cT[r];
        __syncthreads();
    }

    // Tb = bf16round(T) * diag(beta) -> Ah (reuse)
    {
        int c4 = (t & 7) * 4;
        #pragma unroll
        for (int i = 0; i < 4; i++) {
            int cth = c4 + i;
            float tvv = (float)Th[r8 * 40 + cth];
            tvv = __bfloat162float(__float2bfloat16(tvv));
            Ah[r8 * 40 + cth] = (_Float16)(tvv * sbeta[cth]);
        }
    }
    __syncthreads();

    // u = Tb @ v ; w = Tb @ kn  (u straight to C-frag file; -w into Qh rows)
    {
        U4H8 aT[2];
        aT[0].u = *(const uint4*)&Ah[(0 * 16 + lm) * 40 + quad * 8];
        aT[1].u = *(const uint4*)&Ah[(1 * 16 + lm) * 40 + quad * 8];
        #pragma unroll
        for (int e = 0; e < 2; e++) {
            int ntt = wv * 2 + e;
            U4H8 bV, bK;
            bV.u = *(const uint4*)&VT[(ntt * 16 + lm) * 40 + quad * 8];
            bK.u = *(const uint4*)&KT[(ntt * 16 + lm) * 40 + quad * 8];
            #pragma unroll
            for (int mt2 = 0; mt2 < 2; mt2++) {
                f32x4 z = {0.f, 0.f, 0.f, 0.f};
                f32x4 cU = __builtin_amdgcn_mfma_f32_16x16x32_f16(aT[mt2].h, bV.h, z, 0, 0, 0);
                f32x4 cW = __builtin_amdgcn_mfma_f32_16x16x32_f16(aT[mt2].h, bK.h, z, 0, 0, 0);
                uint2 ou;
                ou.x = pack2(cU[0], cU[1]); ou.y = pack2(cU[2], cU[3]);
                uf[(((long)blk * 2 + mt2) * 8 + ntt) * 64 + l] = ou;
                #pragma unroll
                for (int r = 0; r < 4; r++)
                    Qh[(mt2 * 16 + quad * 4 + r) * 136 + ntt * 16 + lm] = (_Float16)(-cW[r]);
            }
        }
    }
    __syncthreads();
    // wneg pack from Qh
    #pragma unroll
    for (int i = 0; i < 2; i++) {
        int slot = t + i * 256;
        int f = slot >> 6, ln = slot & 63, flm = ln & 15, fq = ln >> 4;
        int mt2 = f >> 2, kt = f & 3;
        wnegf[((long)blk * 8 + f) * 64 + ln] =
            *(const uint4*)&Qh[(mt2 * 16 + flm) * 136 + kt * 32 + fq * 8];
    }
}

// ---------------- Phase 3 ----------------
struct Frags {
    uint4 aW[2][4];
    uint4 aQ[2][4];
    uint4 aK[8];
    uint4 aAt[2];
    uint2 aU[2];
};

__global__ __launch_bounds__(64, 1) void phase3_kernel(
    const uint4* __restrict__ wnegf, const uint4* __restrict__ qnf,
    const uint4* __restrict__ ktf, const uint4* __restrict__ atf,
    const uint2* __restrict__ uf,
    float* __restrict__ o_out, float* __restrict__ S_out)
{
    __shared__ alignas(16) _Float16 S16[16 * 136];  // [dv local][dk] XOR-swizzled
    __shared__ alignas(16) _Float16 U16[16 * 40];   // [dv local][s]

    const int l = threadIdx.x;
    const int lm = l & 15, quad = l >> 4, dvl = lm & 7;
    const int bh = blockIdx.x & 15;   // same bh -> same (blockIdx%8) -> same XCD
    const int w = blockIdx.x >> 4;    // dv stripe 0..7
    const int dv = w * 16 + lm;

    f32x4 accS[8];
    #pragma unroll
    for (int mt = 0; mt < 8; mt++) accS[mt] = (f32x4){0.f, 0.f, 0.f, 0.f};

    auto loadf = [&](Frags& f, int nc) {
        long blk = (long)bh * NCHUNK + nc;
        #pragma unroll
        for (int mt2 = 0; mt2 < 2; mt2++) {
            #pragma unroll
            for (int kt = 0; kt < 4; kt++) {
                f.aW[mt2][kt] = wnegf[(blk * 8 + mt2 * 4 + kt) * 64 + l];
                f.aQ[mt2][kt] = qnf[(blk * 8 + mt2 * 4 + kt) * 64 + l];
            }
            f.aAt[mt2] = atf[(blk * 2 + mt2) * 64 + l];
            f.aU[mt2] = uf[((blk * 2 + mt2) * 8 + w) * 64 + l];
        }
        #pragma unroll
        for (int mt = 0; mt < 8; mt++) f.aK[mt] = ktf[(blk * 8 + mt) * 64 + l];
    };

    auto compute = [&](const Frags& f, int nc) {
        // Stage A: accS -> S16 fp16 (swizzled)
        #pragma unroll
        for (int mt = 0; mt < 8; mt++) {
            int dk0 = mt * 16 + quad * 4;
            int phys = (dk0 >> 3) ^ dvl;
            int sub = dk0 & 7;
            uint2 p;
            p.x = pack2(accS[mt][0], accS[mt][1]);
            p.y = pack2(accS[mt][2], accS[mt][3]);
            *(uint2*)&S16[lm * 136 + phys * 8 + sub] = p;
        }
        __builtin_amdgcn_sched_barrier(0);
        // Stage B: u_new = u + (-w)@S ; o_part = q@S
        f32x4 accU[2], accO[2];
        #pragma unroll
        for (int mt2 = 0; mt2 < 2; mt2++) {
            accU[mt2][0] = h2f(f.aU[mt2].x & 0xffffu);
            accU[mt2][1] = h2f(f.aU[mt2].x >> 16);
            accU[mt2][2] = h2f(f.aU[mt2].y & 0xffffu);
            accU[mt2][3] = h2f(f.aU[mt2].y >> 16);
            accO[mt2] = (f32x4){0.f, 0.f, 0.f, 0.f};
        }
        #pragma unroll
        for (int kt = 0; kt < 4; kt++) {
            int phys = (kt * 4 + quad) ^ dvl;
            U4H8 bs;
            bs.u = *(const uint4*)&S16[lm * 136 + phys * 8];
            #pragma unroll
            for (int mt2 = 0; mt2 < 2; mt2++) {
                U4H8 aw, aq;
                aw.u = f.aW[mt2][kt];
                aq.u = f.aQ[mt2][kt];
                accU[mt2] = __builtin_amdgcn_mfma_f32_16x16x32_f16(aw.h, bs.h, accU[mt2], 0, 0, 0);
                accO[mt2] = __builtin_amdgcn_mfma_f32_16x16x32_f16(aq.h, bs.h, accO[mt2], 0, 0, 0);
            }
        }
        // Stage C: u_new -> U16
        #pragma unroll
        for (int mt2 = 0; mt2 < 2; mt2++) {
            int s0 = mt2 * 16 + quad * 4;
            uint2 p;
            p.x = pack2(accU[mt2][0], accU[mt2][1]);
            p.y = pack2(accU[mt2][2], accU[mt2][3]);
            *(uint2*)&U16[lm * 40 + s0] = p;
        }
        __builtin_amdgcn_sched_barrier(0);
        // Stage D: o += attl @ u_new; store o
        U4H8 bu;
        bu.u = *(const uint4*)&U16[lm * 40 + quad * 8];
        const long ob = ((long)bh * LSEQ + (long)nc * C) * DV;
        #pragma unroll
        for (int mt2 = 0; mt2 < 2; mt2++) {
            U4H8 aa;
            aa.u = f.aAt[mt2];
            accO[mt2] = __builtin_amdgcn_mfma_f32_16x16x32_f16(aa.h, bu.h, accO[mt2], 0, 0, 0);
            #pragma unroll
            for (int r = 0; r < 4; r++)
                o_out[ob + (long)(mt2 * 16 + quad * 4 + r) * DV + dv] = accO[mt2][r];
        }
        // Stage E: S += kT @ u_new
        #pragma unroll
        for (int mt = 0; mt < 8; mt++) {
            U4H8 ak;
            ak.u = f.aK[mt];
            accS[mt] = __builtin_amdgcn_mfma_f32_16x16x32_f16(ak.h, bu.h, accS[mt], 0, 0, 0);
        }
    };

    Frags fA, fB;
    loadf(fA, 0);
    #pragma unroll 1
    for (int nc = 0; nc < NCHUNK; nc += 2) {
        loadf(fB, (nc + 1 < NCHUNK - 1) ? nc + 1 : NCHUNK - 1);
        compute(fA, nc);
        loadf(fA, (nc + 2 < NCHUNK - 1) ? nc + 2 : NCHUNK - 1);
        compute(fB, nc + 1);
    }
    // final S
    #pragma unroll
    for (int mt = 0; mt < 8; mt++) {
        #pragma unroll
        for (int r = 0; r < 4; r++)
            S_out[(long)bh * (DK * DV) + (long)(mt * 16 + quad * 4 + r) * DV + dv] = accS[mt][r];
    }
}

extern "C" void kernel_launch(void* const* d_in, const int* in_sizes, int n_in,
                              void* d_out, int out_size, void* d_ws, size_t ws_size,
                              hipStream_t stream) {
    const float* q    = (const float*)d_in[0];
    const float* k    = (const float*)d_in[1];
    const float* v    = (const float*)d_in[2];
    const float* beta = (const float*)d_in[3];

    float* o = (float*)d_out;                      // [b,h,L,dv]
    float* S = o + (long)BH * LSEQ * DV;           // [b,h,dk,dv]

    // workspace: wneg16 + qn16 + kT16 (16.8MB each) + attl16 4.2MB + u16 16.8MB
    const size_t nwq = (size_t)NBLK * 8 * 64;      // uint4 per A-frag file
    uint4* wnegf = (uint4*)d_ws;
    uint4* qnf = wnegf + nwq;
    uint4* ktf = qnf + nwq;
    uint4* atf = ktf + nwq;                        // uses NBLK*2*64 uint4
    uint2* uf  = (uint2*)(atf + (size_t)NBLK * 2 * 64);

    phase2_kernel<<<NBLK, 256, 0, stream>>>(q, k, v, beta, wnegf, qnf, ktf, atf, uf);
    phase3_kernel<<<BH * 8, 64, 0, stream>>>(wnegf, qnf, ktf, atf, uf, o, S);
}

// Round 4
// 233.238 us; speedup vs baseline: 8.7318x; 1.0724x over previous
//
#include <hip/hip_runtime.h>
#include <hip/hip_bf16.h>

// DeltaNet chunkwise delta rule, b=2 h=8 L=4096 dk=dv=128 chunk=32.
// Phase2 (2048 wgs x 64 thr = 1 wave/chunk, NO barriers): all-MFMA chunk-local
//   pass. Loads q/k frag-direct, Gram RAW=k@kT via MFMA, attl^T via MFMA,
//   (I-A)^-1 by nilpotent doubling with T/T^T C-frags in registers, row-major
//   LDS always written from transpose-C-frags (vector b64) and read as b128
//   frags. Emits fp16 frag files (A-frag order) + u in C-frag order.
// Phase3 (128 wgs x 64 thr): per-(bh,dv-stripe) scan, S in MFMA accumulators,
//   conflict-free [(dk>>3)][dv][dk&7] LDS layout for the C->B frag transforms,
//   2-deep register prefetch, no barriers.

#define B 2
#define H 8
#define LSEQ 4096
#define DK 128
#define DV 128
#define C 32
#define NCHUNK (LSEQ / C)      // 128
#define BH (B * H)             // 16
#define NBLK (BH * NCHUNK)     // 2048

typedef _Float16 f16x8 __attribute__((ext_vector_type(8)));
typedef float f32x4 __attribute__((ext_vector_type(4)));

union U4H8 { uint4 u; f16x8 h; };

__device__ inline unsigned short f2h(float f) {
    _Float16 h = (_Float16)f;
    unsigned short u;
    __builtin_memcpy(&u, &h, 2);
    return u;
}
__device__ inline float h2f(unsigned int v) {
    unsigned short s = (unsigned short)v;
    _Float16 h;
    __builtin_memcpy(&h, &s, 2);
    return (float)h;
}
__device__ inline unsigned int pack2(float a, float b) {
    return (unsigned int)f2h(a) | ((unsigned int)f2h(b) << 16);
}
__device__ inline float dot4(float4 a, float4 b) {
    return a.x * b.x + a.y * b.y + a.z * b.z + a.w * b.w;
}
__device__ inline float bf16r(float x) {
    return __bfloat162float(__float2bfloat16(x));
}
__device__ inline uint2 pk4(float v0, float v1, float v2, float v3) {
    uint2 p; p.x = pack2(v0, v1); p.y = pack2(v2, v3); return p;
}

// ---------------- Phase 2 ----------------
// 32x32 row-major LDS buffers use stride 40 halfwords (80B): b64-write and
// b128-read aligned; bank starts 20R+... spread over all 32 banks at floor.
#define S40 40
#define S136 136

__global__ __launch_bounds__(64) void phase2_kernel(
    const float* __restrict__ qg, const float* __restrict__ kg,
    const float* __restrict__ vg, const float* __restrict__ betag,
    uint4* __restrict__ wnegf, uint4* __restrict__ qnf,
    uint4* __restrict__ ktf, uint4* __restrict__ atf,
    uint2* __restrict__ uf)
{
    __shared__ alignas(16) _Float16 sA [32 * S40];
    __shared__ alignas(16) _Float16 sAT[32 * S40];
    __shared__ alignas(16) _Float16 sTT[32 * S40];
    __shared__ alignas(16) _Float16 sTB[32 * S40];   // attl rows, then Tb rows
    __shared__ alignas(16) _Float16 sW [32 * S136];  // -w rows
    __shared__ alignas(16) float sbetaL[32];
    __shared__ alignas(16) float skscL[32];

    const int l = threadIdx.x;
    const int lm = l & 15, qd = l >> 4;
    const int blk = blockIdx.x;
    const long tb = (long)blk * C * DK;
    const f32x4 z4 = {0.f, 0.f, 0.f, 0.f};

    if (l < 32) sbetaL[l] = betag[(long)blk * C + l];

    // ---- load q,k frag-direct (fp16) with fp32 sumsq ----
    U4H8 qF[8], kF[8];
    float ssq[2] = {0.f, 0.f}, ssk[2] = {0.f, 0.f};
    #pragma unroll
    for (int mt = 0; mt < 2; mt++) {
        #pragma unroll
        for (int kt = 0; kt < 4; kt++) {
            const float* qp = qg + tb + (long)(mt * 16 + lm) * DK + kt * 32 + qd * 8;
            const float* kp = kg + tb + (long)(mt * 16 + lm) * DK + kt * 32 + qd * 8;
            float4 a0 = *(const float4*)qp, a1 = *(const float4*)(qp + 4);
            float4 b0 = *(const float4*)kp, b1 = *(const float4*)(kp + 4);
            ssq[mt] += dot4(a0, a0) + dot4(a1, a1);
            ssk[mt] += dot4(b0, b0) + dot4(b1, b1);
            U4H8 x;
            x.u.x = pack2(a0.x, a0.y); x.u.y = pack2(a0.z, a0.w);
            x.u.z = pack2(a1.x, a1.y); x.u.w = pack2(a1.z, a1.w);
            qF[mt * 4 + kt] = x;
            U4H8 y;
            y.u.x = pack2(b0.x, b0.y); y.u.y = pack2(b0.z, b0.w);
            y.u.z = pack2(b1.x, b1.y); y.u.w = pack2(b1.z, b1.w);
            kF[mt * 4 + kt] = y;
        }
    }
    float qsc[2], ksc[2];
    #pragma unroll
    for (int mt = 0; mt < 2; mt++) {
        float s = ssq[mt];
        s += __shfl_xor(s, 16, 64);
        s += __shfl_xor(s, 32, 64);
        qsc[mt] = rsqrtf(s + 1e-6f);
        float t = ssk[mt];
        t += __shfl_xor(t, 16, 64);
        t += __shfl_xor(t, 32, 64);
        ksc[mt] = rsqrtf(t + 1e-6f);
    }
    if (qd == 0) { skscL[lm] = ksc[0]; skscL[16 + lm] = ksc[1]; }

    // ---- attl^T = kraw @ qraw^T, tiles (0,0),(0,1),(1,1) ----
    f32x4 alT[3] = {z4, z4, z4};
    #pragma unroll
    for (int kt = 0; kt < 4; kt++) {
        alT[0] = __builtin_amdgcn_mfma_f32_16x16x32_f16(kF[kt].h,     qF[kt].h,     alT[0], 0, 0, 0);
        alT[1] = __builtin_amdgcn_mfma_f32_16x16x32_f16(kF[kt].h,     qF[4 + kt].h, alT[1], 0, 0, 0);
        alT[2] = __builtin_amdgcn_mfma_f32_16x16x32_f16(kF[4 + kt].h, qF[4 + kt].h, alT[2], 0, 0, 0);
    }
    // ---- qnf (qn = qsc[row]*qraw; row = mt*16+lm is lane-resident) ----
    #pragma unroll
    for (int mt = 0; mt < 2; mt++) {
        _Float16 qs = (_Float16)qsc[mt];
        #pragma unroll
        for (int kt = 0; kt < 4; kt++) {
            U4H8 x;
            x.h = qF[mt * 4 + kt].h * qs;
            qnf[((long)blk * 8 + mt * 4 + kt) * 64 + l] = x.u;
        }
    }
    // ---- RAW = kraw @ kraw^T, all 4 tiles ----
    f32x4 rw[4] = {z4, z4, z4, z4};   // idx mi*2+ni
    #pragma unroll
    for (int kt = 0; kt < 4; kt++) {
        rw[0] = __builtin_amdgcn_mfma_f32_16x16x32_f16(kF[kt].h,     kF[kt].h,     rw[0], 0, 0, 0);
        rw[1] = __builtin_amdgcn_mfma_f32_16x16x32_f16(kF[kt].h,     kF[4 + kt].h, rw[1], 0, 0, 0);
        rw[2] = __builtin_amdgcn_mfma_f32_16x16x32_f16(kF[4 + kt].h, kF[kt].h,     rw[2], 0, 0, 0);
        rw[3] = __builtin_amdgcn_mfma_f32_16x16x32_f16(kF[4 + kt].h, kF[4 + kt].h, rw[3], 0, 0, 0);
    }

    // per-lane scale vectors (from LDS; wave-synchronous)
    float4 b4[2], ks4[2];
    b4[0]  = *(const float4*)&sbetaL[qd * 4];      b4[1]  = *(const float4*)&sbetaL[16 + qd * 4];
    ks4[0] = *(const float4*)&skscL[qd * 4];       ks4[1] = *(const float4*)&skscL[16 + qd * 4];
    const float bcol0 = sbetaL[lm], bcol1 = sbetaL[16 + lm];
    const float bA4[2] = {(&b4[0].x)[0], 0.f}; (void)bA4;

    // ---- attl rows into sTB; val = qsc[R]*ksc[c]*raw, mask c<=R ----
    {
        *(uint2*)&sTB[lm * S40 + 16 + qd * 4] = (uint2){0u, 0u};   // zero region r0-15,c16-31
        float v[4];
        // (0,0): R=lm, c=qd*4+r
        #pragma unroll
        for (int r = 0; r < 4; r++) {
            int c = qd * 4 + r;
            v[r] = (c <= lm) ? (qsc[0] * (&ks4[0].x)[r] * alT[0][r]) : 0.f;
        }
        *(uint2*)&sTB[lm * S40 + qd * 4] = pk4(v[0], v[1], v[2], v[3]);
        // (0,1): R=16+lm, c=qd*4+r (always <=)
        #pragma unroll
        for (int r = 0; r < 4; r++) v[r] = qsc[1] * (&ks4[0].x)[r] * alT[1][r];
        *(uint2*)&sTB[(16 + lm) * S40 + qd * 4] = pk4(v[0], v[1], v[2], v[3]);
        // (1,1): R=16+lm, c=16+qd*4+r, mask qd*4+r<=lm
        #pragma unroll
        for (int r = 0; r < 4; r++) {
            int c = qd * 4 + r;
            v[r] = (c <= lm) ? (qsc[1] * (&ks4[1].x)[r] * alT[2][r]) : 0.f;
        }
        *(uint2*)&sTB[(16 + lm) * S40 + 16 + qd * 4] = pk4(v[0], v[1], v[2], v[3]);
    }
    // ---- atf ----
    #pragma unroll
    for (int f = 0; f < 2; f++) {
        uint4 x = *(const uint4*)&sTB[(f * 16 + lm) * S40 + qd * 8];
        atf[((long)blk * 2 + f) * 64 + l] = x;
    }

    // ---- A rows / A^T rows / T^T rows; Tc / TTc C-frag inits ----
    {
        float v[4];
        // zero regions
        *(uint2*)&sA [lm * S40 + 16 + qd * 4]        = (uint2){0u, 0u};
        *(uint2*)&sAT[(16 + lm) * S40 + qd * 4]      = (uint2){0u, 0u};
        *(uint2*)&sTT[(16 + lm) * S40 + qd * 4]      = (uint2){0u, 0u};
        // A rows: tile(mi,ni) -> A[R=ni*16+lm][c=mi*16+qd*4+r], val=-b[R]ksc[R]ksc[c]raw, mask c<R
        #pragma unroll
        for (int r = 0; r < 4; r++) {
            int c = qd * 4 + r;
            v[r] = (c < lm) ? (-bcol0 * ksc[0] * (&ks4[0].x)[r] * rw[0][r]) : 0.f;
        }
        *(uint2*)&sA[lm * S40 + qd * 4] = pk4(v[0], v[1], v[2], v[3]);
        #pragma unroll
        for (int r = 0; r < 4; r++) v[r] = -bcol1 * ksc[1] * (&ks4[0].x)[r] * rw[1][r];
        *(uint2*)&sA[(16 + lm) * S40 + qd * 4] = pk4(v[0], v[1], v[2], v[3]);
        #pragma unroll
        for (int r = 0; r < 4; r++) {
            int c = qd * 4 + r;
            v[r] = (c < lm) ? (-bcol1 * ksc[1] * (&ks4[1].x)[r] * rw[3][r]) : 0.f;
        }
        *(uint2*)&sA[(16 + lm) * S40 + 16 + qd * 4] = pk4(v[0], v[1], v[2], v[3]);
        // A^T rows: tile(mi,ni) -> AT[R=ni*16+lm][c=mi*16+qd*4+r], val=-b[c]ksc[c]ksc[R]raw, mask c>R
        #pragma unroll
        for (int r = 0; r < 4; r++) {
            int c = qd * 4 + r;
            v[r] = (c > lm) ? (-(&b4[0].x)[r] * (&ks4[0].x)[r] * ksc[0] * rw[0][r]) : 0.f;
        }
        *(uint2*)&sAT[lm * S40 + qd * 4] = pk4(v[0], v[1], v[2], v[3]);
        #pragma unroll
        for (int r = 0; r < 4; r++) v[r] = -(&b4[1].x)[r] * (&ks4[1].x)[r] * ksc[0] * rw[2][r];
        *(uint2*)&sAT[lm * S40 + 16 + qd * 4] = pk4(v[0], v[1], v[2], v[3]);
        #pragma unroll
        for (int r = 0; r < 4; r++) {
            int c = qd * 4 + r;
            v[r] = (c > lm) ? (-(&b4[1].x)[r] * (&ks4[1].x)[r] * ksc[1] * rw[3][r]) : 0.f;
        }
        *(uint2*)&sAT[(16 + lm) * S40 + 16 + qd * 4] = pk4(v[0], v[1], v[2], v[3]);
        // T^T rows: same as A^T plus identity on diag
        #pragma unroll
        for (int r = 0; r < 4; r++) {
            int c = qd * 4 + r;
            v[r] = (c > lm) ? (-(&b4[0].x)[r] * (&ks4[0].x)[r] * ksc[0] * rw[0][r])
                            : ((c == lm) ? 1.0f : 0.f);
        }
        *(uint2*)&sTT[lm * S40 + qd * 4] = pk4(v[0], v[1], v[2], v[3]);
        #pragma unroll
        for (int r = 0; r < 4; r++) v[r] = -(&b4[1].x)[r] * (&ks4[1].x)[r] * ksc[0] * rw[2][r];
        *(uint2*)&sTT[lm * S40 + 16 + qd * 4] = pk4(v[0], v[1], v[2], v[3]);
        #pragma unroll
        for (int r = 0; r < 4; r++) {
            int c = qd * 4 + r;
            v[r] = (c > lm) ? (-(&b4[1].x)[r] * (&ks4[1].x)[r] * ksc[1] * rw[3][r])
                            : ((c == lm) ? 1.0f : 0.f);
        }
        *(uint2*)&sTT[(16 + lm) * S40 + 16 + qd * 4] = pk4(v[0], v[1], v[2], v[3]);
    }
    // Tc tiles {(0,0),(1,0),(1,1)}: row=mi*16+qd*4+r, col=ni*16+lm
    // TTc tiles {(0,0),(0,1),(1,1)}: row'=mi*16+qd*4+r, col'=ni*16+lm
    f32x4 Tc[3], TTc[3];
    #pragma unroll
    for (int r = 0; r < 4; r++) {
        int rr = qd * 4 + r;
        // Tc[0] (0,0)
        Tc[0][r] = (lm < rr) ? (-(&b4[0].x)[r] * (&ks4[0].x)[r] * ksc[0] * rw[0][r])
                             : ((lm == rr) ? 1.0f : 0.f);
        // Tc[1] (1,0): row=16+rr, col=lm -> always col<row
        Tc[1][r] = -(&b4[1].x)[r] * (&ks4[1].x)[r] * ksc[0] * rw[2][r];
        // Tc[2] (1,1)
        Tc[2][r] = (lm < rr) ? (-(&b4[1].x)[r] * (&ks4[1].x)[r] * ksc[1] * rw[3][r])
                             : ((lm == rr) ? 1.0f : 0.f);
        // TTc[0] (0,0): row'=rr, col'=lm, mask row'<col'
        TTc[0][r] = (rr < lm) ? (-bcol0 * ksc[0] * (&ks4[0].x)[r] * rw[0][r])
                              : ((rr == lm) ? 1.0f : 0.f);
        // TTc[1] (0,1): row'=rr, col'=16+lm -> always <
        TTc[1][r] = -bcol1 * ksc[1] * (&ks4[0].x)[r] * rw[1][r];
        // TTc[2] (1,1)
        TTc[2][r] = (rr < lm) ? (-bcol1 * ksc[1] * (&ks4[1].x)[r] * rw[3][r])
                              : ((rr == lm) ? 1.0f : 0.f);
    }

    // ---- nilpotent doubling: 4 levels of {A<-A^2; T<-T+A*T} ----
    #pragma unroll
    for (int p = 0; p < 4; p++) {
        U4H8 AF[2], ATF[2], TTF[2];
        AF[0].u  = *(const uint4*)&sA [lm * S40 + qd * 8];
        AF[1].u  = *(const uint4*)&sA [(16 + lm) * S40 + qd * 8];
        ATF[0].u = *(const uint4*)&sAT[lm * S40 + qd * 8];
        ATF[1].u = *(const uint4*)&sAT[(16 + lm) * S40 + qd * 8];
        TTF[0].u = *(const uint4*)&sTT[lm * S40 + qd * 8];
        TTF[1].u = *(const uint4*)&sTT[(16 + lm) * S40 + qd * 8];

        f32x4 A2_00 = __builtin_amdgcn_mfma_f32_16x16x32_f16(AF[0].h, ATF[0].h, z4, 0, 0, 0);
        f32x4 A2_10 = __builtin_amdgcn_mfma_f32_16x16x32_f16(AF[1].h, ATF[0].h, z4, 0, 0, 0);
        f32x4 A2_11 = __builtin_amdgcn_mfma_f32_16x16x32_f16(AF[1].h, ATF[1].h, z4, 0, 0, 0);
        f32x4 A2T_00 = __builtin_amdgcn_mfma_f32_16x16x32_f16(ATF[0].h, AF[0].h, z4, 0, 0, 0);
        f32x4 A2T_01 = __builtin_amdgcn_mfma_f32_16x16x32_f16(ATF[0].h, AF[1].h, z4, 0, 0, 0);
        f32x4 A2T_11 = __builtin_amdgcn_mfma_f32_16x16x32_f16(ATF[1].h, AF[1].h, z4, 0, 0, 0);

        // A rows <- A2T tiles (mask c<R)
        {
            float v[4];
            #pragma unroll
            for (int r = 0; r < 4; r++) { int c = qd * 4 + r; v[r] = (c < lm) ? A2T_00[r] : 0.f; }
            *(uint2*)&sA[lm * S40 + qd * 4] = pk4(v[0], v[1], v[2], v[3]);
            *(uint2*)&sA[(16 + lm) * S40 + qd * 4] = pk4(A2T_01[0], A2T_01[1], A2T_01[2], A2T_01[3]);
            #pragma unroll
            for (int r = 0; r < 4; r++) { int c = qd * 4 + r; v[r] = (c < lm) ? A2T_11[r] : 0.f; }
            *(uint2*)&sA[(16 + lm) * S40 + 16 + qd * 4] = pk4(v[0], v[1], v[2], v[3]);
        }
        // A^T rows <- A2 tiles (mask c>R)
        if (p < 3) {
            float v[4];
            #pragma unroll
            for (int r = 0; r < 4; r++) { int c = qd * 4 + r; v[r] = (c > lm) ? A2_00[r] : 0.f; }
            *(uint2*)&sAT[lm * S40 + qd * 4] = pk4(v[0], v[1], v[2], v[3]);
            *(uint2*)&sAT[lm * S40 + 16 + qd * 4] = pk4(A2_10[0], A2_10[1], A2_10[2], A2_10[3]);
            #pragma unroll
            for (int r = 0; r < 4; r++) { int c = qd * 4 + r; v[r] = (c > lm) ? A2_11[r] : 0.f; }
            *(uint2*)&sAT[(16 + lm) * S40 + 16 + qd * 4] = pk4(v[0], v[1], v[2], v[3]);
        }
        // read new A frags
        U4H8 AnF[2];
        AnF[0].u = *(const uint4*)&sA[lm * S40 + qd * 8];
        AnF[1].u = *(const uint4*)&sA[(16 + lm) * S40 + qd * 8];
        // T updates (C-accumulate in regs)
        Tc[0]  = __builtin_amdgcn_mfma_f32_16x16x32_f16(AnF[0].h, TTF[0].h, Tc[0], 0, 0, 0);
        Tc[1]  = __builtin_amdgcn_mfma_f32_16x16x32_f16(AnF[1].h, TTF[0].h, Tc[1], 0, 0, 0);
        Tc[2]  = __builtin_amdgcn_mfma_f32_16x16x32_f16(AnF[1].h, TTF[1].h, Tc[2], 0, 0, 0);
        TTc[0] = __builtin_amdgcn_mfma_f32_16x16x32_f16(TTF[0].h, AnF[0].h, TTc[0], 0, 0, 0);
        TTc[1] = __builtin_amdgcn_mfma_f32_16x16x32_f16(TTF[0].h, AnF[1].h, TTc[1], 0, 0, 0);
        TTc[2] = __builtin_amdgcn_mfma_f32_16x16x32_f16(TTF[1].h, AnF[1].h, TTc[2], 0, 0, 0);
        // T^T rows <- Tc tiles (no mask; zeros are exact)
        if (p < 3) {
            *(uint2*)&sTT[lm * S40 + qd * 4]             = pk4(Tc[0][0], Tc[0][1], Tc[0][2], Tc[0][3]);
            *(uint2*)&sTT[lm * S40 + 16 + qd * 4]        = pk4(Tc[1][0], Tc[1][1], Tc[1][2], Tc[1][3]);
            *(uint2*)&sTT[(16 + lm) * S40 + 16 + qd * 4] = pk4(Tc[2][0], Tc[2][1], Tc[2][2], Tc[2][3]);
        }
    }

    // ---- Tb rows (bf16-round then *beta[col]) into sTB ----
    {
        *(uint2*)&sTB[lm * S40 + 16 + qd * 4] = (uint2){0u, 0u};
        float v[4];
        #pragma unroll
        for (int r = 0; r < 4; r++) v[r] = bf16r(TTc[0][r]) * (&b4[0].x)[r];
        *(uint2*)&sTB[lm * S40 + qd * 4] = pk4(v[0], v[1], v[2], v[3]);
        #pragma unroll
        for (int r = 0; r < 4; r++) v[r] = bf16r(TTc[1][r]) * (&b4[0].x)[r];
        *(uint2*)&sTB[(16 + lm) * S40 + qd * 4] = pk4(v[0], v[1], v[2], v[3]);
        #pragma unroll
        for (int r = 0; r < 4; r++) v[r] = bf16r(TTc[2][r]) * (&b4[1].x)[r];
        *(uint2*)&sTB[(16 + lm) * S40 + 16 + qd * 4] = pk4(v[0], v[1], v[2], v[3]);
    }
    U4H8 TbF[2];
    TbF[0].u = *(const uint4*)&sTB[lm * S40 + qd * 8];
    TbF[1].u = *(const uint4*)&sTB[(16 + lm) * S40 + qd * 8];

    // ---- u, w, ktf, wneg ----
    float kscj[8];
    #pragma unroll
    for (int j = 0; j < 8; j++) kscj[j] = skscL[qd * 8 + j];
    #pragma unroll
    for (int nt = 0; nt < 8; nt++) {
        U4H8 bV, bK;
        #pragma unroll
        for (int j = 0; j < 8; j++) {
            const long ro = tb + (long)(qd * 8 + j) * DK + nt * 16 + lm;
            bV.h[j] = (_Float16)vg[ro];
            bK.h[j] = (_Float16)(kg[ro] * kscj[j]);
        }
        ktf[((long)blk * 8 + nt) * 64 + l] = bK.u;
        f32x4 u0 = __builtin_amdgcn_mfma_f32_16x16x32_f16(TbF[0].h, bV.h, z4, 0, 0, 0);
        f32x4 u1 = __builtin_amdgcn_mfma_f32_16x16x32_f16(TbF[1].h, bV.h, z4, 0, 0, 0);
        uf[(((long)blk * 2 + 0) * 8 + nt) * 64 + l] = pk4(u0[0], u0[1], u0[2], u0[3]);
        uf[(((long)blk * 2 + 1) * 8 + nt) * 64 + l] = pk4(u1[0], u1[1], u1[2], u1[3]);
        f32x4 w0 = __builtin_amdgcn_mfma_f32_16x16x32_f16(TbF[0].h, bK.h, z4, 0, 0, 0);
        f32x4 w1 = __builtin_amdgcn_mfma_f32_16x16x32_f16(TbF[1].h, bK.h, z4, 0, 0, 0);
        #pragma unroll
        for (int r = 0; r < 4; r++) {
            sW[(qd * 4 + r) * S136 + nt * 16 + lm]        = (_Float16)(-w0[r]);
            sW[(16 + qd * 4 + r) * S136 + nt * 16 + lm]   = (_Float16)(-w1[r]);
        }
    }
    #pragma unroll
    for (int mt2 = 0; mt2 < 2; mt2++) {
        #pragma unroll
        for (int kt = 0; kt < 4; kt++) {
            uint4 x = *(const uint4*)&sW[(mt2 * 16 + lm) * S136 + kt * 32 + qd * 8];
            wnegf[((long)blk * 8 + mt2 * 4 + kt) * 64 + l] = x;
        }
    }
}

// ---------------- Phase 3 ----------------
struct Frags {
    uint4 aW[2][4];
    uint4 aQ[2][4];
    uint4 aK[8];
    uint4 aAt[2];
    uint2 aU[2];
};

__global__ __launch_bounds__(64, 1) void phase3_kernel(
    const uint4* __restrict__ wnegf, const uint4* __restrict__ qnf,
    const uint4* __restrict__ ktf, const uint4* __restrict__ atf,
    const uint2* __restrict__ uf,
    float* __restrict__ o_out, float* __restrict__ S_out)
{
    // conflict-free layouts: element (dk,dvl) at ((dk>>3)*16+dvl)*8 + (dk&7)
    __shared__ alignas(16) _Float16 S16[16 * 16 * 8];  // 4KB
    __shared__ alignas(16) _Float16 U16[4 * 16 * 8];   // 1KB

    const int l = threadIdx.x;
    const int lm = l & 15, quad = l >> 4;
    const int bh = blockIdx.x & 15;   // same bh -> same XCD group
    const int w = blockIdx.x >> 4;    // dv stripe 0..7
    const int dv = w * 16 + lm;

    f32x4 accS[8];
    #pragma unroll
    for (int mt = 0; mt < 8; mt++) accS[mt] = (f32x4){0.f, 0.f, 0.f, 0.f};

    auto loadf = [&](Frags& f, int nc) {
        long blk = (long)bh * NCHUNK + nc;
        #pragma unroll
        for (int mt2 = 0; mt2 < 2; mt2++) {
            #pragma unroll
            for (int kt = 0; kt < 4; kt++) {
                f.aW[mt2][kt] = wnegf[(blk * 8 + mt2 * 4 + kt) * 64 + l];
                f.aQ[mt2][kt] = qnf[(blk * 8 + mt2 * 4 + kt) * 64 + l];
            }
            f.aAt[mt2] = atf[(blk * 2 + mt2) * 64 + l];
            f.aU[mt2] = uf[((blk * 2 + mt2) * 8 + w) * 64 + l];
        }
        #pragma unroll
        for (int mt = 0; mt < 8; mt++) f.aK[mt] = ktf[(blk * 8 + mt) * 64 + l];
    };

    auto compute = [&](const Frags& f, int nc) {
        // Stage A: accS (C-frag) -> S16
        #pragma unroll
        for (int mt = 0; mt < 8; mt++) {
            int g = 2 * mt + (quad >> 1);
            int sub = (quad & 1) * 4;
            *(uint2*)&S16[(g * 16 + lm) * 8 + sub] =
                pk4(accS[mt][0], accS[mt][1], accS[mt][2], accS[mt][3]);
        }
        // Stage B: u_new = u + (-w)@S ; o_part = q@S
        f32x4 accU[2], accO[2];
        #pragma unroll
        for (int mt2 = 0; mt2 < 2; mt2++) {
            accU[mt2][0] = h2f(f.aU[mt2].x & 0xffffu);
            accU[mt2][1] = h2f(f.aU[mt2].x >> 16);
            accU[mt2][2] = h2f(f.aU[mt2].y & 0xffffu);
            accU[mt2][3] = h2f(f.aU[mt2].y >> 16);
            accO[mt2] = (f32x4){0.f, 0.f, 0.f, 0.f};
        }
        #pragma unroll
        for (int kt = 0; kt < 4; kt++) {
            U4H8 bs;
            bs.u = *(const uint4*)&S16[((kt * 4 + quad) * 16 + lm) * 8];
            #pragma unroll
            for (int mt2 = 0; mt2 < 2; mt2++) {
                U4H8 aw, aq;
                aw.u = f.aW[mt2][kt];
                aq.u = f.aQ[mt2][kt];
                accU[mt2] = __builtin_amdgcn_mfma_f32_16x16x32_f16(aw.h, bs.h, accU[mt2], 0, 0, 0);
                accO[mt2] = __builtin_amdgcn_mfma_f32_16x16x32_f16(aq.h, bs.h, accO[mt2], 0, 0, 0);
            }
        }
        // Stage C: u_new -> U16
        #pragma unroll
        for (int mt2 = 0; mt2 < 2; mt2++) {
            int g = 2 * mt2 + (quad >> 1);
            int sub = (quad & 1) * 4;
            *(uint2*)&U16[(g * 16 + lm) * 8 + sub] =
                pk4(accU[mt2][0], accU[mt2][1], accU[mt2][2], accU[mt2][3]);
        }
        // Stage D: o += attl @ u_new; store o
        U4H8 bu;
        bu.u = *(const uint4*)&U16[(quad * 16 + lm) * 8];
        const long ob = ((long)bh * LSEQ + (long)nc * C) * DV;
        #pragma unroll
        for (int mt2 = 0; mt2 < 2; mt2++) {
            U4H8 aa;
            aa.u = f.aAt[mt2];
            accO[mt2] = __builtin_amdgcn_mfma_f32_16x16x32_f16(aa.h, bu.h, accO[mt2], 0, 0, 0);
            #pragma unroll
            for (int r = 0; r < 4; r++)
                o_out[ob + (long)(mt2 * 16 + quad * 4 + r) * DV + dv] = accO[mt2][r];
        }
        // Stage E: S += kT @ u_new
        #pragma unroll
        for (int mt = 0; mt < 8; mt++) {
            U4H8 ak;
            ak.u = f.aK[mt];
            accS[mt] = __builtin_amdgcn_mfma_f32_16x16x32_f16(ak.h, bu.h, accS[mt], 0, 0, 0);
        }
    };

    Frags fA, fB;
    loadf(fA, 0);
    #pragma unroll 1
    for (int nc = 0; nc < NCHUNK; nc += 2) {
        loadf(fB, (nc + 1 < NCHUNK - 1) ? nc + 1 : NCHUNK - 1);
        compute(fA, nc);
        loadf(fA, (nc + 2 < NCHUNK - 1) ? nc + 2 : NCHUNK - 1);
        compute(fB, nc + 1);
    }
    // final S
    #pragma unroll
    for (int mt = 0; mt < 8; mt++) {
        #pragma unroll
        for (int r = 0; r < 4; r++)
            S_out[(long)bh * (DK * DV) + (long)(mt * 16 + quad * 4 + r) * DV + dv] = accS[mt][r];
    }
}

extern "C" void kernel_launch(void* const* d_in, const int* in_sizes, int n_in,
                              void* d_out, int out_size, void* d_ws, size_t ws_size,
                              hipStream_t stream) {
    const float* q    = (const float*)d_in[0];
    const float* k    = (const float*)d_in[1];
    const float* v    = (const float*)d_in[2];
    const float* beta = (const float*)d_in[3];

    float* o = (float*)d_out;                      // [b,h,L,dv]
    float* S = o + (long)BH * LSEQ * DV;           // [b,h,dk,dv]

    const size_t nwq = (size_t)NBLK * 8 * 64;      // uint4 per A-frag file
    uint4* wnegf = (uint4*)d_ws;
    uint4* qnf = wnegf + nwq;
    uint4* ktf = qnf + nwq;
    uint4* atf = ktf + nwq;                        // NBLK*2*64 uint4
    uint2* uf  = (uint2*)(atf + (size_t)NBLK * 2 * 64);

    phase2_kernel<<<NBLK, 64, 0, stream>>>(q, k, v, beta, wnegf, qnf, ktf, atf, uf);
    phase3_kernel<<<BH * 8, 64, 0, stream>>>(wnegf, qnf, ktf, atf, uf, o, S);
}